// Round 8
// baseline (1484.026 us; speedup 1.0000x reference)
//
#include <hip/hip_runtime.h>
#include <hip/hip_cooperative_groups.h>

namespace cg = cooperative_groups;

#define PN 10000
#define UN 8000
#define BN 4096
#define NGE 320000
#define NDE 320000
#define NUE 400000
#define NPUE 400000
#define INV_T 5.0f
// cumulative edge offsets: geo, tar, src, up, pu
#define E0 320000
#define E1 640000
#define E2 960000
#define E3 1360000
#define E4 1760000
#define META_INTS 96006
#define ZN (3 * PN + META_INTS)

typedef __attribute__((ext_vector_type(8))) short short8;
typedef __attribute__((ext_vector_type(4))) float f32x4;
typedef unsigned short u16;
typedef unsigned int u32;

__device__ __forceinline__ u16 f2bf(float x) {
    u32 u = __float_as_uint(x);
    return (u16)((u + 0x7FFFu + ((u >> 16) & 1u)) >> 16);
}

struct MArgs {
    const float *poi, *uemb, *wgg, *bgg, *wgs, *bgs, *wgc, *bgc, *fw, *fb;
    const float *geo_vals, *src_vals, *tar_vals, *up_vals, *pu_vals;
    const int *geo_rows, *geo_cols, *src_rows, *src_cols, *tar_rows, *tar_cols;
    const int *up_rows, *up_cols, *pu_rows, *pu_cols, *user_idx;
    float *rowsum, *colsum, *pos;
    u16 *ngb, *nsb;
    float *U0, *P0, *P1, *P2, *P3, *P4;
    int *M;
    int *geo_rp, *geo_cur, *tar_rp, *tar_cur, *src_rp, *src_cur;
    int *up_rp, *up_cur, *pu_rp, *pu_cur;
    int2 *geo_ent, *tar_ent, *src_ent, *up_ent, *pu_ent;
    float *out_bu, *out_fp, *out_loss;
};

// ---------------- device bodies ----------------
__device__ __forceinline__ void dev_spmm_core(int row, int lane,
        const int* __restrict__ rp, const int2* __restrict__ ent,
        const float* __restrict__ x, const float* __restrict__ add,
        const float* __restrict__ avg_a, const float* __restrict__ avg_b,
        float* __restrict__ y, u16* __restrict__ yb, int nrows, int mode) {
    if (row >= nrows) return;
    size_t o = (size_t)row * 64 + lane;
    int s = rp[row], e = rp[row + 1];
    float acc = add ? add[o] : 0.0f;
    int p = s;
    for (; p + 4 <= e; p += 4) {
        int2 c0 = ent[p], c1 = ent[p + 1], c2 = ent[p + 2], c3 = ent[p + 3];
        float w0 = x[(size_t)c0.x * 64 + lane];
        float w1 = x[(size_t)c1.x * 64 + lane];
        float w2 = x[(size_t)c2.x * 64 + lane];
        float w3 = x[(size_t)c3.x * 64 + lane];
        acc = fmaf(__int_as_float(c0.y), w0, acc);
        acc = fmaf(__int_as_float(c1.y), w1, acc);
        acc = fmaf(__int_as_float(c2.y), w2, acc);
        acc = fmaf(__int_as_float(c3.y), w3, acc);
    }
    for (; p < e; ++p) {
        int2 c = ent[p];
        acc = fmaf(__int_as_float(c.y), x[(size_t)c.x * 64 + lane], acc);
    }
    if (mode == 0) { y[o] = acc; return; }
    float v = (avg_a[o] + avg_b[o] + acc) * (1.0f / 3.0f);
    float ss = v * v;
#pragma unroll
    for (int off = 32; off > 0; off >>= 1) ss += __shfl_xor(ss, off, 64);
    float d = fmaxf(sqrtf(ss), 1e-12f);
    float r = v / d;
    y[o] = r;
    yb[o] = f2bf(r);
}

__device__ void dev_gates(int u, const MArgs& A, char* smem) {
    float* W  = (float*)smem;                   // 64*64 f32 = 16384 B
    float* Bv = (float*)(smem + 16384);         // 192 f32
    float* pe = (float*)(smem + 16384 + 768);   // 256 f32
    int tid = threadIdx.x;
    int r = tid >> 6, j = tid & 63;
    int r0 = u * 4;
    pe[tid] = A.poi[(r0 + r) * 64 + j];
    if (tid < 64)       Bv[tid] = A.bgg[tid];
    else if (tid < 128) Bv[tid] = A.bgs[tid - 64];
    else if (tid < 192) Bv[tid] = A.bgc[tid - 128];
    const float* Ws[3] = {A.wgg, A.wgs, A.wgc};
    float* Os[3] = {A.P0, A.P1, A.P2};
    __syncthreads();
    float pj = pe[r * 64 + j];
#pragma unroll
    for (int g = 0; g < 3; g++) {
        for (int t = tid; t < 4096; t += 256) W[t] = Ws[g][t];
        __syncthreads();
        float acc = Bv[g * 64 + j];
#pragma unroll
        for (int k = 0; k < 64; k++) acc = fmaf(pe[r * 64 + k], W[k * 64 + j], acc);
        Os[g][(r0 + r) * 64 + j] = pj * (1.0f / (1.0f + __expf(-acc)));
        __syncthreads();
    }
}

__device__ void dev_scan(int* __restrict__ cnt, int* __restrict__ rp, int n, int nnz, char* smem) {
    int* part = (int*)smem;
    int tid = threadIdx.x;
    int chunk = (n + 255) >> 8;
    int base = tid * chunk;
    int s = 0;
    for (int k = 0; k < chunk; k++) {
        int i = base + k;
        if (i < n) s += cnt[i];
    }
    part[tid] = s;
    __syncthreads();
    for (int off = 1; off < 256; off <<= 1) {
        int v = (tid >= off) ? part[tid - off] : 0;
        __syncthreads();
        part[tid] += v;
        __syncthreads();
    }
    int pre = (tid > 0) ? part[tid - 1] : 0;
    for (int k = 0; k < chunk; k++) {
        int i = base + k;
        if (i < n) {
            int c = cnt[i];
            rp[i] = pre;
            cnt[i] = pre;
            pre += c;
        }
    }
    if (tid == 0) rp[n] = nnz;
    __syncthreads();
}

__device__ void dev_fuse(int u, const MArgs& A, char* smem) {
    float* msg = (float*)smem;   // 4 * 448 f32 = 7168 B
    int tid = threadIdx.x, lane = tid & 63, r = tid >> 6;
    int row = u * 4 + r;
    float a0 = 0.f, a1 = 0.f, a2 = 0.f;
    {
        int s = A.up_rp[row], e = A.up_rp[row + 1];
        for (int p = s; p < e; ++p) {
            int2 c = A.up_ent[p];
            float v = __int_as_float(c.y);
            size_t o = (size_t)c.x * 64 + lane;
            a0 = fmaf(v, A.P0[o], a0);
            a1 = fmaf(v, A.P1[o], a1);
            a2 = fmaf(v, A.P2[o], a2);
        }
    }
    msg[r * 448 + 0 * 64 + lane] = a0;
    msg[r * 448 + 1 * 64 + lane] = a1;
    msg[r * 448 + 2 * 64 + lane] = a2;
    msg[r * 448 + 3 * 64 + lane] = a0 * a1;
    msg[r * 448 + 4 * 64 + lane] = a0 * a2;
    msg[r * 448 + 5 * 64 + lane] = a1 * a2;
    msg[r * 448 + 6 * 64 + lane] = a0 * a1 * a2;
    __syncthreads();
    float acc = A.fb[lane];
#pragma unroll 8
    for (int k = 0; k < 448; k++) acc = fmaf(msg[r * 448 + k], A.fw[k * 64 + lane], acc);
    size_t o = (size_t)row * 64 + lane;
    float uu = A.uemb[o];
    A.U0[o] = acc + uu + acc * uu;
    __syncthreads();
}

__device__ void dev_infonce(int t, const MArgs& A, char* smem) {
    u16* Al = (u16*)smem;
    u16* Bl = (u16*)(smem + 18432);
    float* red = (float*)smem;      // reused after frags cached
    int tid = threadIdx.x;
    int bx = t % 79, by = t / 79;
    int i0 = bx * 128, j0 = by * 128;
    const uint4 zero4 = make_uint4(0, 0, 0, 0);
    for (int u = tid; u < 1024; u += 256) {
        int row = u >> 3, ch = u & 7;
        int ga = i0 + row, gb = j0 + row;
        uint4 va = (ga < PN) ? ((const uint4*)A.ngb)[(size_t)ga * 8 + ch] : zero4;
        uint4 vb = (gb < PN) ? ((const uint4*)A.nsb)[(size_t)gb * 8 + ch] : zero4;
        ((uint4*)Al)[row * 9 + ch] = va;
        ((uint4*)Bl)[row * 9 + ch] = vb;
    }
    __syncthreads();
    int wv = tid >> 6, lane = tid & 63;
    int wr = (wv & 1) * 64;
    int wc = (wv >> 1) * 64;
    int quad = lane >> 4, l15 = lane & 15;

    short8 af[4][2], bf[4][2];
#pragma unroll
    for (int tt = 0; tt < 4; tt++)
#pragma unroll
        for (int ks = 0; ks < 2; ks++) {
            af[tt][ks] = *(const short8*)&Al[(wr + tt * 16 + l15) * 72 + ks * 32 + quad * 8];
            bf[tt][ks] = *(const short8*)&Bl[(wc + tt * 16 + l15) * 72 + ks * 32 + quad * 8];
        }
    __syncthreads();

    f32x4 acc[4][4];
#pragma unroll
    for (int rt = 0; rt < 4; rt++)
#pragma unroll
        for (int ct = 0; ct < 4; ct++) {
            f32x4 c = {0.f, 0.f, 0.f, 0.f};
            c = __builtin_amdgcn_mfma_f32_16x16x32_bf16(af[rt][0], bf[ct][0], c, 0, 0, 0);
            c = __builtin_amdgcn_mfma_f32_16x16x32_bf16(af[rt][1], bf[ct][1], c, 0, 0, 0);
            acc[rt][ct] = c;
        }

    float rs[4][4];
#pragma unroll
    for (int rt = 0; rt < 4; rt++)
#pragma unroll
        for (int g = 0; g < 4; g++) rs[rt][g] = 0.f;
    float cs[4] = {0.f, 0.f, 0.f, 0.f};

    bool interior = (i0 + 128 <= PN) && (j0 + 128 <= PN) && (i0 != j0);
    if (interior) {
#pragma unroll
        for (int rt = 0; rt < 4; rt++)
#pragma unroll
            for (int ct = 0; ct < 4; ct++) {
                float csum = 0.f;
#pragma unroll
                for (int g = 0; g < 4; g++) {
                    float e = __expf(acc[rt][ct][g] * INV_T);
                    rs[rt][g] += e;
                    csum += e;
                }
                cs[ct] += csum;
            }
    } else {
#pragma unroll
        for (int rt = 0; rt < 4; rt++) {
            int ibase = i0 + wr + rt * 16 + quad * 4;
#pragma unroll
            for (int ct = 0; ct < 4; ct++) {
                int j = j0 + wc + ct * 16 + l15;
                bool jv = (j < PN);
                float csum = 0.f;
#pragma unroll
                for (int g = 0; g < 4; g++) {
                    int i = ibase + g;
                    float e = 0.f;
                    if (jv && i < PN) {
                        e = __expf(acc[rt][ct][g] * INV_T);
                        if (i == j) A.pos[i] = e;
                    }
                    rs[rt][g] += e;
                    csum += e;
                }
                cs[ct] += csum;
            }
        }
    }
#pragma unroll
    for (int off = 16; off <= 32; off <<= 1)
#pragma unroll
        for (int ct = 0; ct < 4; ct++) cs[ct] += __shfl_xor(cs[ct], off, 64);
    if (quad == 0) {
#pragma unroll
        for (int ct = 0; ct < 4; ct++) {
            int j = j0 + wc + ct * 16 + l15;
            if (j < PN) atomicAdd(&A.colsum[j], cs[ct]);
        }
    }
    int slot = (wv >> 1) * 16 + l15;
#pragma unroll
    for (int rt = 0; rt < 4; rt++)
#pragma unroll
        for (int g = 0; g < 4; g++) {
            int rl = wr + rt * 16 + quad * 4 + g;
            red[slot * 131 + rl] = rs[rt][g];
        }
    __syncthreads();
    if (tid < 128) {
        float sum = 0.f;
#pragma unroll
        for (int s2 = 0; s2 < 32; s2++) sum += red[s2 * 131 + tid];
        int i = i0 + tid;
        if (i < PN) atomicAdd(&A.rowsum[i], sum);
    }
    __syncthreads();
}

__device__ void dev_puout(int u, const MArgs& A) {
    int lane = threadIdx.x & 63;
    int row = u * 4 + (threadIdx.x >> 6);
    size_t o = (size_t)row * 64 + lane;
    float acc = A.P2[o];
    int s = A.pu_rp[row], e = A.pu_rp[row + 1];
    int p = s;
    for (; p + 4 <= e; p += 4) {
        int2 c0 = A.pu_ent[p], c1 = A.pu_ent[p + 1], c2 = A.pu_ent[p + 2], c3 = A.pu_ent[p + 3];
        float w0 = A.U0[(size_t)c0.x * 64 + lane];
        float w1 = A.U0[(size_t)c1.x * 64 + lane];
        float w2 = A.U0[(size_t)c2.x * 64 + lane];
        float w3 = A.U0[(size_t)c3.x * 64 + lane];
        acc = fmaf(__int_as_float(c0.y), w0, acc);
        acc = fmaf(__int_as_float(c1.y), w1, acc);
        acc = fmaf(__int_as_float(c2.y), w2, acc);
        acc = fmaf(__int_as_float(c3.y), w3, acc);
    }
    for (; p < e; ++p) {
        int2 c = A.pu_ent[p];
        acc = fmaf(__int_as_float(c.y), A.U0[(size_t)c.x * 64 + lane], acc);
    }
    float ss = acc * acc;
#pragma unroll
    for (int off = 32; off > 0; off >>= 1) ss += __shfl_xor(ss, off, 64);
    float d = fmaxf(sqrtf(ss), 1e-12f);
    float f = acc / d + A.P0[o] + A.P1[o];
    A.P3[o] = f;
    A.out_fp[o] = f;
}

// ================= cooperative mega-kernel =================
__global__ __launch_bounds__(256, 3) void mega_kernel(MArgs A) {
    __shared__ __align__(16) char smem[36864];
    cg::grid_group grid = cg::this_grid();
    const int tid = threadIdx.x;
    const int G = gridDim.x;

    // P0: zero stats + CSR counters
    for (int u = blockIdx.x; u < (ZN + 255) / 256; u += G) {
        int i = u * 256 + tid;
        if (i < 3 * PN) A.rowsum[i] = 0.0f;
        else if (i < ZN) A.M[i - 3 * PN] = 0;
    }
    grid.sync();
    // P1: hist (6875) + gates (2500)
    for (int u = blockIdx.x; u < 6875 + 2500; u += G) {
        if (u < 6875) {
            int e = u * 256 + tid;
            if (e < E0)      atomicAdd(&A.geo_cur[A.geo_rows[e]], 1);
            else if (e < E1) atomicAdd(&A.tar_cur[A.tar_rows[e - E0]], 1);
            else if (e < E2) atomicAdd(&A.src_cur[A.src_rows[e - E1]], 1);
            else if (e < E3) atomicAdd(&A.up_cur[A.up_rows[e - E2]], 1);
            else if (e < E4) atomicAdd(&A.pu_cur[A.pu_rows[e - E3]], 1);
        } else {
            dev_gates(u - 6875, A, smem);
        }
    }
    grid.sync();
    // P2: 5 scans
    for (int u = blockIdx.x; u < 5; u += G) {
        switch (u) {
            case 0: dev_scan(A.geo_cur, A.geo_rp, PN, NGE, smem); break;
            case 1: dev_scan(A.tar_cur, A.tar_rp, PN, NDE, smem); break;
            case 2: dev_scan(A.src_cur, A.src_rp, PN, NDE, smem); break;
            case 3: dev_scan(A.up_cur,  A.up_rp,  UN, NUE, smem); break;
            default: dev_scan(A.pu_cur, A.pu_rp, PN, NPUE, smem); break;
        }
    }
    grid.sync();
    // P3: scatter
    for (int u = blockIdx.x; u < 6875; u += G) {
        int e = u * 256 + tid;
        const int* rr; const int* kk; const float* vv; int* cu; int2* en; int idx;
        bool ok = true;
        if (e < E0)      { rr = A.geo_rows; kk = A.geo_cols; vv = A.geo_vals; cu = A.geo_cur; en = A.geo_ent; idx = e; }
        else if (e < E1) { rr = A.tar_rows; kk = A.tar_cols; vv = A.tar_vals; cu = A.tar_cur; en = A.tar_ent; idx = e - E0; }
        else if (e < E2) { rr = A.src_rows; kk = A.src_cols; vv = A.src_vals; cu = A.src_cur; en = A.src_ent; idx = e - E1; }
        else if (e < E3) { rr = A.up_rows;  kk = A.up_cols;  vv = A.up_vals;  cu = A.up_cur;  en = A.up_ent;  idx = e - E2; }
        else if (e < E4) { rr = A.pu_rows;  kk = A.pu_cols;  vv = A.pu_vals;  cu = A.pu_cur;  en = A.pu_ent;  idx = e - E3; }
        else ok = false;
        if (ok) {
            int p = atomicAdd(&cu[rr[idx]], 1);
            en[p] = make_int2(kk[idx], __float_as_int(vv[idx]));
        }
    }
    grid.sync();
    // P4: geo1 (x1_g = A*g + g -> P3) + tar1 (m1 = T*sg -> P4)
    {
        int lane = tid & 63, rr = tid >> 6;
        for (int u = blockIdx.x; u < 5000; u += G) {
            if (u < 2500)
                dev_spmm_core(u * 4 + rr, lane, A.geo_rp, A.geo_ent, A.P0, A.P0, nullptr, nullptr, A.P3, nullptr, PN, 0);
            else
                dev_spmm_core((u - 2500) * 4 + rr, lane, A.tar_rp, A.tar_ent, A.P1, nullptr, nullptr, nullptr, A.P4, nullptr, PN, 0);
        }
    }
    grid.sync();
    // P5: geo-final: x2 = A*x1 + x1; ng = norm((g+x1+x2)/3) -> P0, ngb
    {
        int lane = tid & 63, rr = tid >> 6;
        for (int u = blockIdx.x; u < 2500; u += G)
            dev_spmm_core(u * 4 + rr, lane, A.geo_rp, A.geo_ent, A.P3, A.P3, A.P0, A.P3, A.P0, A.ngb, PN, 1);
    }
    grid.sync();
    // P6: x1_s = S*m1 + sg -> P3
    {
        int lane = tid & 63, rr = tid >> 6;
        for (int u = blockIdx.x; u < 2500; u += G)
            dev_spmm_core(u * 4 + rr, lane, A.src_rp, A.src_ent, A.P4, A.P1, nullptr, nullptr, A.P3, nullptr, PN, 0);
    }
    grid.sync();
    // P7: m2 = T*x1_s -> P4
    {
        int lane = tid & 63, rr = tid >> 6;
        for (int u = blockIdx.x; u < 2500; u += G)
            dev_spmm_core(u * 4 + rr, lane, A.tar_rp, A.tar_ent, A.P3, nullptr, nullptr, nullptr, A.P4, nullptr, PN, 0);
    }
    grid.sync();
    // P8: x2 = S*m2 + x1_s; ns = norm((sg+x1_s+x2)/3) -> P1, nsb
    {
        int lane = tid & 63, rr = tid >> 6;
        for (int u = blockIdx.x; u < 2500; u += G)
            dev_spmm_core(u * 4 + rr, lane, A.src_rp, A.src_ent, A.P4, A.P3, A.P1, A.P3, A.P1, A.nsb, PN, 1);
    }
    grid.sync();
    // P9: InfoNCE (6241 tiles) + spmm3_fuse (2000 units)
    for (int u = blockIdx.x; u < 6241 + 2000; u += G) {
        if (u < 6241) dev_infonce(u, A, smem);
        else          dev_fuse(u - 6241, A, smem);
    }
    grid.sync();
    // P10: hg_pois = col_g + pu*hg; fusion_out -> P3 + out_fp
    for (int u = blockIdx.x; u < 2500; u += G) dev_puout(u, A);
    grid.sync();
    // P11: users_struct = up * fusion -> U0
    {
        int lane = tid & 63, rr = tid >> 6;
        for (int u = blockIdx.x; u < 2000; u += G)
            dev_spmm_core(u * 4 + rr, lane, A.up_rp, A.up_ent, A.P3, nullptr, nullptr, nullptr, A.U0, nullptr, UN, 0);
    }
    grid.sync();
    // P12: batch_users (1024) + loss (1)
    for (int u = blockIdx.x; u < 1025; u += G) {
        if (u < 1024) {
            int lane = tid & 63;
            int b = u * 4 + (tid >> 6);
            int r = A.user_idx[b];
            float v = A.U0[(size_t)r * 64 + lane];
            float s = v * v;
#pragma unroll
            for (int off = 32; off > 0; off >>= 1) s += __shfl_xor(s, off, 64);
            float d = fmaxf(sqrtf(s), 1e-12f);
            A.out_bu[(size_t)b * 64 + lane] = v / d;
        } else {
            float* red = (float*)smem;
            float acc = 0.0f;
            for (int i = tid; i < PN; i += 256) {
                float p = A.pos[i];
                acc += -logf(p / (A.rowsum[i] + 1e-8f) + 1e-8f);
                acc += -logf(p / (A.colsum[i] + 1e-8f) + 1e-8f);
            }
            red[tid] = acc;
            __syncthreads();
            for (int s = 128; s > 0; s >>= 1) {
                if (tid < s) red[tid] += red[tid + s];
                __syncthreads();
            }
            if (tid == 0) A.out_loss[0] = 0.5f * red[0] / (float)PN;
            __syncthreads();
        }
    }
}

// ================= R7 fallback kernels (used only if cooperative launch fails) =================
__global__ void zero_kernel(float* __restrict__ a, int na, int* __restrict__ b, int nb) {
    int i = blockIdx.x * 256 + threadIdx.x;
    if (i < na) a[i] = 0.0f;
    else { int j = i - na; if (j < nb) b[j] = 0; }
}

__global__ void gates3_fb_kernel(MArgs A) {
    __shared__ __align__(16) char smem[36864];
    dev_gates(blockIdx.x, A, smem);
}

__global__ void hist_fb_kernel(MArgs A) {
    int e = blockIdx.x * 256 + threadIdx.x;
    if (e < E0)      atomicAdd(&A.geo_cur[A.geo_rows[e]], 1);
    else if (e < E1) atomicAdd(&A.tar_cur[A.tar_rows[e - E0]], 1);
    else if (e < E2) atomicAdd(&A.src_cur[A.src_rows[e - E1]], 1);
    else if (e < E3) atomicAdd(&A.up_cur[A.up_rows[e - E2]], 1);
    else if (e < E4) atomicAdd(&A.pu_cur[A.pu_rows[e - E3]], 1);
}

__global__ void scan_fb_kernel(MArgs A) {
    __shared__ __align__(16) char smem[36864];
    switch (blockIdx.x) {
        case 0: dev_scan(A.geo_cur, A.geo_rp, PN, NGE, smem); break;
        case 1: dev_scan(A.tar_cur, A.tar_rp, PN, NDE, smem); break;
        case 2: dev_scan(A.src_cur, A.src_rp, PN, NDE, smem); break;
        case 3: dev_scan(A.up_cur,  A.up_rp,  UN, NUE, smem); break;
        default: dev_scan(A.pu_cur, A.pu_rp, PN, NPUE, smem); break;
    }
}

__global__ void scatter_fb_kernel(MArgs A) {
    int e = blockIdx.x * 256 + threadIdx.x;
    const int* rr; const int* kk; const float* vv; int* cu; int2* en; int idx;
    if (e < E0)      { rr = A.geo_rows; kk = A.geo_cols; vv = A.geo_vals; cu = A.geo_cur; en = A.geo_ent; idx = e; }
    else if (e < E1) { rr = A.tar_rows; kk = A.tar_cols; vv = A.tar_vals; cu = A.tar_cur; en = A.tar_ent; idx = e - E0; }
    else if (e < E2) { rr = A.src_rows; kk = A.src_cols; vv = A.src_vals; cu = A.src_cur; en = A.src_ent; idx = e - E1; }
    else if (e < E3) { rr = A.up_rows;  kk = A.up_cols;  vv = A.up_vals;  cu = A.up_cur;  en = A.up_ent;  idx = e - E2; }
    else if (e < E4) { rr = A.pu_rows;  kk = A.pu_cols;  vv = A.pu_vals;  cu = A.pu_cur;  en = A.pu_ent;  idx = e - E3; }
    else return;
    int p = atomicAdd(&cu[rr[idx]], 1);
    en[p] = make_int2(kk[idx], __float_as_int(vv[idx]));
}

// step: 0=geo1+tar1 (grid 5000), 1=geo2fin, 2=s1, 3=tar2, 4=s2fin, 5=upfinal
__global__ void spmm_fb_kernel(MArgs A, int step) {
    int lane = threadIdx.x & 63, rr = threadIdx.x >> 6;
    int u = blockIdx.x;
    switch (step) {
        case 0:
            if (u < 2500) dev_spmm_core(u * 4 + rr, lane, A.geo_rp, A.geo_ent, A.P0, A.P0, nullptr, nullptr, A.P3, nullptr, PN, 0);
            else dev_spmm_core((u - 2500) * 4 + rr, lane, A.tar_rp, A.tar_ent, A.P1, nullptr, nullptr, nullptr, A.P4, nullptr, PN, 0);
            break;
        case 1: dev_spmm_core(u * 4 + rr, lane, A.geo_rp, A.geo_ent, A.P3, A.P3, A.P0, A.P3, A.P0, A.ngb, PN, 1); break;
        case 2: dev_spmm_core(u * 4 + rr, lane, A.src_rp, A.src_ent, A.P4, A.P1, nullptr, nullptr, A.P3, nullptr, PN, 0); break;
        case 3: dev_spmm_core(u * 4 + rr, lane, A.tar_rp, A.tar_ent, A.P3, nullptr, nullptr, nullptr, A.P4, nullptr, PN, 0); break;
        case 4: dev_spmm_core(u * 4 + rr, lane, A.src_rp, A.src_ent, A.P4, A.P3, A.P1, A.P3, A.P1, A.nsb, PN, 1); break;
        default: dev_spmm_core(u * 4 + rr, lane, A.up_rp, A.up_ent, A.P3, nullptr, nullptr, nullptr, A.U0, nullptr, UN, 0); break;
    }
}

__global__ __launch_bounds__(256) void infonce_fb_kernel(MArgs A) {
    __shared__ __align__(16) char smem[36864];
    dev_infonce(blockIdx.x, A, smem);
}

__global__ void fuse_fb_kernel(MArgs A) {
    __shared__ __align__(16) char smem[36864];
    dev_fuse(blockIdx.x, A, smem);
}

__global__ void puout_fb_kernel(MArgs A) { dev_puout(blockIdx.x, A); }

__global__ void batch_loss_fb_kernel(MArgs A) {
    __shared__ float red[256];
    int tid = threadIdx.x;
    if ((int)blockIdx.x < 1024) {
        int lane = tid & 63;
        int b = blockIdx.x * 4 + (tid >> 6);
        int r = A.user_idx[b];
        float v = A.U0[(size_t)r * 64 + lane];
        float s = v * v;
#pragma unroll
        for (int off = 32; off > 0; off >>= 1) s += __shfl_xor(s, off, 64);
        float d = fmaxf(sqrtf(s), 1e-12f);
        A.out_bu[(size_t)b * 64 + lane] = v / d;
        return;
    }
    float acc = 0.0f;
    for (int i = tid; i < PN; i += 256) {
        float p = A.pos[i];
        acc += -logf(p / (A.rowsum[i] + 1e-8f) + 1e-8f);
        acc += -logf(p / (A.colsum[i] + 1e-8f) + 1e-8f);
    }
    red[tid] = acc;
    __syncthreads();
    for (int s = 128; s > 0; s >>= 1) {
        if (tid < s) red[tid] += red[tid + s];
        __syncthreads();
    }
    if (tid == 0) A.out_loss[0] = 0.5f * red[0] / (float)PN;
}

extern "C" void kernel_launch(void* const* d_in, const int* in_sizes, int n_in,
                              void* d_out, int out_size, void* d_ws, size_t ws_size,
                              hipStream_t stream) {
    (void)in_sizes; (void)n_in; (void)out_size; (void)ws_size;
    const int PD = PN * 64, UD = UN * 64;

    MArgs A;
    A.poi  = (const float*)d_in[0];
    A.uemb = (const float*)d_in[1];
    A.wgg  = (const float*)d_in[2];
    A.bgg  = (const float*)d_in[3];
    A.wgs  = (const float*)d_in[4];
    A.bgs  = (const float*)d_in[5];
    A.wgc  = (const float*)d_in[6];
    A.bgc  = (const float*)d_in[7];
    A.fw   = (const float*)d_in[8];
    A.fb   = (const float*)d_in[9];
    A.geo_vals = (const float*)d_in[10];
    A.src_vals = (const float*)d_in[11];
    A.tar_vals = (const float*)d_in[12];
    A.up_vals  = (const float*)d_in[13];
    A.pu_vals  = (const float*)d_in[14];
    A.geo_rows = (const int*)d_in[15];
    A.geo_cols = (const int*)d_in[16];
    A.src_rows = (const int*)d_in[17];
    A.src_cols = (const int*)d_in[18];
    A.tar_rows = (const int*)d_in[19];
    A.tar_cols = (const int*)d_in[20];
    A.up_rows  = (const int*)d_in[21];
    A.up_cols  = (const int*)d_in[22];
    A.pu_rows  = (const int*)d_in[23];
    A.pu_cols  = (const int*)d_in[24];
    A.user_idx = (const int*)d_in[25];

    float* F = (float*)d_ws;
    A.rowsum = F;
    A.colsum = A.rowsum + PN;
    A.pos    = A.colsum + PN;
    A.ngb    = (u16*)(F + 3 * PN);
    A.nsb    = A.ngb + PD;
    A.U0     = F + 3 * PN + PD;
    A.P0     = A.U0 + UD;
    A.P1     = A.P0 + PD;
    A.P2     = A.P1 + PD;
    A.P3     = A.P2 + PD;
    A.P4     = A.P3 + PD;
    A.M      = (int*)(A.P4 + PD);
    A.geo_rp = A.M;                  A.geo_cur = A.geo_rp + PN + 1;
    A.tar_rp = A.geo_cur + PN;       A.tar_cur = A.tar_rp + PN + 1;
    A.src_rp = A.tar_cur + PN;       A.src_cur = A.src_rp + PN + 1;
    A.up_rp  = A.src_cur + PN;       A.up_cur  = A.up_rp + UN + 1;
    A.pu_rp  = A.up_cur + UN;        A.pu_cur  = A.pu_rp + PN + 1;
    A.geo_ent = (int2*)(A.M + META_INTS);
    A.tar_ent = A.geo_ent + NGE;
    A.src_ent = A.tar_ent + NDE;
    A.up_ent  = A.src_ent + NDE;
    A.pu_ent  = A.up_ent + NUE;

    A.out_bu = (float*)d_out;
    A.out_fp = A.out_bu + (size_t)BN * 64;
    A.out_loss = A.out_fp + (size_t)PN * 64;

    // ---- cooperative mega-kernel launch with runtime co-residency guard
    int occ = 0;
    hipError_t oe = hipOccupancyMaxActiveBlocksPerMultiprocessor(&occ, mega_kernel, 256, 0);
    hipError_t rc = hipErrorUnknown;
    if (oe == hipSuccess && occ >= 1) {
        int nblk = occ * 256;             // 256 CUs on MI355X
        if (nblk > 1024) nblk = 1024;
        void* params[1] = { (void*)&A };
        rc = hipLaunchCooperativeKernel((const void*)mega_kernel, dim3(nblk), dim3(256),
                                        params, 0, stream);
    }
    if (rc != hipSuccess) {
        (void)hipGetLastError();   // clear error state
        // ---- fallback: R7 15-dispatch sequence
        const int RB = PN / 4, UB = UN / 4;
        const int NTOTB = (E4 + 255) / 256;
        zero_kernel<<<(ZN + 255) / 256, 256, 0, stream>>>(A.rowsum, 3 * PN, A.M, META_INTS);
        hist_fb_kernel<<<NTOTB, 256, 0, stream>>>(A);
        scan_fb_kernel<<<5, 256, 0, stream>>>(A);
        scatter_fb_kernel<<<NTOTB, 256, 0, stream>>>(A);
        gates3_fb_kernel<<<RB, 256, 0, stream>>>(A);
        spmm_fb_kernel<<<2 * RB, 256, 0, stream>>>(A, 0);
        spmm_fb_kernel<<<RB, 256, 0, stream>>>(A, 1);
        spmm_fb_kernel<<<RB, 256, 0, stream>>>(A, 2);
        spmm_fb_kernel<<<RB, 256, 0, stream>>>(A, 3);
        spmm_fb_kernel<<<RB, 256, 0, stream>>>(A, 4);
        infonce_fb_kernel<<<6241, 256, 0, stream>>>(A);
        fuse_fb_kernel<<<UB, 256, 0, stream>>>(A);
        puout_fb_kernel<<<RB, 256, 0, stream>>>(A);
        spmm_fb_kernel<<<UB, 256, 0, stream>>>(A, 5);
        batch_loss_fb_kernel<<<1025, 256, 0, stream>>>(A);
    }
}

// Round 9
// 760.309 us; speedup vs baseline: 1.9519x; 1.9519x over previous
//
#include <hip/hip_runtime.h>

#define PN 10000
#define UN 8000
#define BN 4096
#define NGE 320000
#define NDE 320000
#define NUE 400000
#define NPUE 400000
#define INV_T 5.0f
// cumulative edge offsets: geo, tar, src, up, pu
#define E0 320000
#define E1 640000
#define E2 960000
#define E3 1360000
#define E4 1760000
#define META_INTS 96006
#define ZN (3 * PN + META_INTS)

typedef __attribute__((ext_vector_type(8))) short short8;
typedef __attribute__((ext_vector_type(4))) float f32x4;
typedef unsigned short u16;
typedef unsigned int u32;

__device__ __forceinline__ u16 f2bf(float x) {
    u32 u = __float_as_uint(x);
    return (u16)((u + 0x7FFFu + ((u >> 16) & 1u)) >> 16);
}

struct MArgs {
    const float *poi, *uemb, *wgg, *bgg, *wgs, *bgs, *wgc, *bgc, *fw, *fb;
    const float *geo_vals, *src_vals, *tar_vals, *up_vals, *pu_vals;
    const int *geo_rows, *geo_cols, *src_rows, *src_cols, *tar_rows, *tar_cols;
    const int *up_rows, *up_cols, *pu_rows, *pu_cols, *user_idx;
    float *rowsum, *colsum, *pos;
    u16 *ngb, *nsb;
    float *U0, *P0, *P1, *P2, *P3, *P4;
    int *M;
    int *geo_rp, *geo_cur, *tar_rp, *tar_cur, *src_rp, *src_cur;
    int *up_rp, *up_cur, *pu_rp, *pu_cur;
    int *geo_ent, *tar_ent, *src_ent, *up_ent, *pu_ent;   // 4B local edge idx
    float *out_bu, *out_fp, *out_loss;
};

// ---------------- CSR SpMM core (4B edge-index entries; wave per row) ----------------
// ALIAS RULES: y may alias add/avg_a/avg_b (same-thread elementwise); y must NEVER alias x.
__device__ __forceinline__ void dev_spmm4(int row, int lane,
        const int* __restrict__ rp, const int* __restrict__ ent,
        const int* __restrict__ cols, const float* __restrict__ vals,
        const float* __restrict__ x, const float* __restrict__ add,
        const float* __restrict__ avg_a, const float* __restrict__ avg_b,
        float* __restrict__ y, u16* __restrict__ yb, int nrows, int mode) {
    if (row >= nrows) return;
    size_t o = (size_t)row * 64 + lane;
    int s = rp[row], e = rp[row + 1];
    float acc = add ? add[o] : 0.0f;
    int p = s;
    for (; p + 4 <= e; p += 4) {
        int i0 = ent[p], i1 = ent[p + 1], i2 = ent[p + 2], i3 = ent[p + 3];
        int c0 = cols[i0], c1 = cols[i1], c2 = cols[i2], c3 = cols[i3];
        float v0 = vals[i0], v1 = vals[i1], v2 = vals[i2], v3 = vals[i3];
        float w0 = x[(size_t)c0 * 64 + lane];
        float w1 = x[(size_t)c1 * 64 + lane];
        float w2 = x[(size_t)c2 * 64 + lane];
        float w3 = x[(size_t)c3 * 64 + lane];
        acc = fmaf(v0, w0, acc);
        acc = fmaf(v1, w1, acc);
        acc = fmaf(v2, w2, acc);
        acc = fmaf(v3, w3, acc);
    }
    for (; p < e; ++p) {
        int i = ent[p];
        acc = fmaf(vals[i], x[(size_t)cols[i] * 64 + lane], acc);
    }
    if (mode == 0) { y[o] = acc; return; }
    float v = (avg_a[o] + avg_b[o] + acc) * (1.0f / 3.0f);
    float ss = v * v;
#pragma unroll
    for (int off = 32; off > 0; off >>= 1) ss += __shfl_xor(ss, off, 64);
    float d = fmaxf(sqrtf(ss), 1e-12f);
    float r = v / d;
    y[o] = r;
    yb[o] = f2bf(r);
}

// ---------------- single gate: out = pe * sigmoid(pe @ W + b) ----------------
__device__ void dev_gate(int u, const float* __restrict__ poi, const float* __restrict__ wg,
                         const float* __restrict__ bg, float* __restrict__ og, char* smem) {
    float* W  = (float*)smem;                    // 4096 f32
    float* Bv = (float*)(smem + 16384);          // 64 f32
    float* pe = (float*)(smem + 16384 + 256);    // 256 f32
    int tid = threadIdx.x;
    for (int t = tid; t < 4096; t += 256) W[t] = wg[t];
    if (tid < 64) Bv[tid] = bg[tid];
    int r = tid >> 6, j = tid & 63;
    int r0 = u * 4;
    pe[r * 64 + j] = poi[(r0 + r) * 64 + j];
    __syncthreads();
    float acc = Bv[j];
#pragma unroll
    for (int k = 0; k < 64; k++) acc = fmaf(pe[r * 64 + k], W[k * 64 + j], acc);
    float pj = pe[r * 64 + j];
    og[(r0 + r) * 64 + j] = pj * (1.0f / (1.0f + __expf(-acc)));
}

// ================= D1: zero stats + CSR counters =================
__global__ void zero_kernel(MArgs A) {
    int i = blockIdx.x * 256 + threadIdx.x;
    if (i < 3 * PN) A.rowsum[i] = 0.0f;
    else if (i < ZN) A.M[i - 3 * PN] = 0;
}

// ================= D2: hist (6875) + geo/seq gates (2x2500) =================
__global__ void hist_gates_kernel(MArgs A) {
    __shared__ __align__(16) char smem[17664];
    int u = blockIdx.x;
    if (u < 6875) {
        int e = u * 256 + threadIdx.x;
        if (e < E0)      atomicAdd(&A.geo_cur[A.geo_rows[e]], 1);
        else if (e < E1) atomicAdd(&A.tar_cur[A.tar_rows[e - E0]], 1);
        else if (e < E2) atomicAdd(&A.src_cur[A.src_rows[e - E1]], 1);
        else if (e < E3) atomicAdd(&A.up_cur[A.up_rows[e - E2]], 1);
        else if (e < E4) atomicAdd(&A.pu_cur[A.pu_rows[e - E3]], 1);
    } else if (u < 6875 + 2500) {
        dev_gate(u - 6875, A.poi, A.wgg, A.bgg, A.P0, smem);          // geo_g -> P0
    } else {
        dev_gate(u - 9375, A.poi, A.wgs, A.bgs, A.P1, smem);          // seq_g -> P1
    }
}

// ================= D3: 5 scans =================
__global__ void scan_kernel(MArgs A) {
    __shared__ int part[256];
    int* cnt; int* rp; int n; int nnz;
    switch (blockIdx.x) {
        case 0: cnt = A.geo_cur; rp = A.geo_rp; n = PN; nnz = NGE; break;
        case 1: cnt = A.tar_cur; rp = A.tar_rp; n = PN; nnz = NDE; break;
        case 2: cnt = A.src_cur; rp = A.src_rp; n = PN; nnz = NDE; break;
        case 3: cnt = A.up_cur;  rp = A.up_rp;  n = UN; nnz = NUE; break;
        default: cnt = A.pu_cur; rp = A.pu_rp;  n = PN; nnz = NPUE; break;
    }
    int tid = threadIdx.x;
    int chunk = (n + 255) >> 8;
    int base = tid * chunk;
    int s = 0;
    for (int k = 0; k < chunk; k++) {
        int i = base + k;
        if (i < n) s += cnt[i];
    }
    part[tid] = s;
    __syncthreads();
    for (int off = 1; off < 256; off <<= 1) {
        int v = (tid >= off) ? part[tid - off] : 0;
        __syncthreads();
        part[tid] += v;
        __syncthreads();
    }
    int pre = (tid > 0) ? part[tid - 1] : 0;
    for (int k = 0; k < chunk; k++) {
        int i = base + k;
        if (i < n) {
            int c = cnt[i];
            rp[i] = pre;
            cnt[i] = pre;   // becomes cursor
            pre += c;
        }
    }
    if (tid == 0) rp[n] = nnz;
}

// ================= D4: scatter 4B local edge idx =================
__global__ void scatter_kernel(MArgs A) {
    int e = blockIdx.x * 256 + threadIdx.x;
    const int* rr; int* cu; int* en; int idx;
    if (e < E0)      { rr = A.geo_rows; cu = A.geo_cur; en = A.geo_ent; idx = e; }
    else if (e < E1) { rr = A.tar_rows; cu = A.tar_cur; en = A.tar_ent; idx = e - E0; }
    else if (e < E2) { rr = A.src_rows; cu = A.src_cur; en = A.src_ent; idx = e - E1; }
    else if (e < E3) { rr = A.up_rows;  cu = A.up_cur;  en = A.up_ent;  idx = e - E2; }
    else if (e < E4) { rr = A.pu_rows;  cu = A.pu_cur;  en = A.pu_ent;  idx = e - E3; }
    else return;
    int p = atomicAdd(&cu[rr[idx]], 1);
    en[p] = idx;
}

// ================= D5-D8, D11: SpMM phases =================
// step 0: geo1 (x1_g=A*g+g: P0->P3) || tar1 (m1=T*sg: P1->P4)          grid 5000
// step 1: geo2fin (x2=A*x1+x1; ng->P0,ngb) || s1 (x1_s=S*m1+sg: ->P2)  grid 5000
// step 2: tar2 (m2=T*x1_s: P2->P3) || gate_col (->P4)                  grid 5000
// step 3: s2fin (x2=S*m2+x1_s; ns->P1,nsb)                             grid 2500
// step 4: users_struct = up * fusion(P3) -> U0                         grid 2000
__global__ __launch_bounds__(256) void spmm_step_kernel(MArgs A, int step) {
    __shared__ __align__(16) char smem[17664];
    int tid = threadIdx.x;
    int lane = tid & 63, w = tid >> 6;
    int u = blockIdx.x;
    if (step == 0) {
        if (u < 2500) dev_spmm4(u * 4 + w, lane, A.geo_rp, A.geo_ent, A.geo_cols, A.geo_vals,
                                A.P0, A.P0, nullptr, nullptr, A.P3, nullptr, PN, 0);
        else dev_spmm4((u - 2500) * 4 + w, lane, A.tar_rp, A.tar_ent, A.tar_cols, A.tar_vals,
                       A.P1, nullptr, nullptr, nullptr, A.P4, nullptr, PN, 0);
    } else if (step == 1) {
        if (u < 2500) dev_spmm4(u * 4 + w, lane, A.geo_rp, A.geo_ent, A.geo_cols, A.geo_vals,
                                A.P3, A.P3, A.P0, A.P3, A.P0, A.ngb, PN, 1);
        else dev_spmm4((u - 2500) * 4 + w, lane, A.src_rp, A.src_ent, A.src_cols, A.src_vals,
                       A.P4, A.P1, nullptr, nullptr, A.P2, nullptr, PN, 0);
    } else if (step == 2) {
        if (u < 2500) dev_spmm4(u * 4 + w, lane, A.tar_rp, A.tar_ent, A.tar_cols, A.tar_vals,
                                A.P2, nullptr, nullptr, nullptr, A.P3, nullptr, PN, 0);
        else dev_gate(u - 2500, A.poi, A.wgc, A.bgc, A.P4, smem);
    } else if (step == 3) {
        dev_spmm4(u * 4 + w, lane, A.src_rp, A.src_ent, A.src_cols, A.src_vals,
                  A.P3, A.P2, A.P1, A.P2, A.P1, A.nsb, PN, 1);
    } else {
        dev_spmm4(u * 4 + w, lane, A.up_rp, A.up_ent, A.up_cols, A.up_vals,
                  A.P3, nullptr, nullptr, nullptr, A.U0, nullptr, UN, 0);
    }
}

// ================= D9: MFMA InfoNCE (6241) + spmm3_fuse (2000) =================
__device__ void dev_infonce(int t, const MArgs& A, char* smem) {
    u16* Al = (u16*)smem;
    u16* Bl = (u16*)(smem + 18432);
    float* red = (float*)smem;      // reused after frags cached
    int tid = threadIdx.x;
    int bx = t % 79, by = t / 79;
    int i0 = bx * 128, j0 = by * 128;
    const uint4 zero4 = make_uint4(0, 0, 0, 0);
    for (int u = tid; u < 1024; u += 256) {
        int row = u >> 3, ch = u & 7;
        int ga = i0 + row, gb = j0 + row;
        uint4 va = (ga < PN) ? ((const uint4*)A.ngb)[(size_t)ga * 8 + ch] : zero4;
        uint4 vb = (gb < PN) ? ((const uint4*)A.nsb)[(size_t)gb * 8 + ch] : zero4;
        ((uint4*)Al)[row * 9 + ch] = va;
        ((uint4*)Bl)[row * 9 + ch] = vb;
    }
    __syncthreads();
    int wv = tid >> 6, lane = tid & 63;
    int wr = (wv & 1) * 64;
    int wc = (wv >> 1) * 64;
    int quad = lane >> 4, l15 = lane & 15;

    short8 af[4][2], bf[4][2];
#pragma unroll
    for (int tt = 0; tt < 4; tt++)
#pragma unroll
        for (int ks = 0; ks < 2; ks++) {
            af[tt][ks] = *(const short8*)&Al[(wr + tt * 16 + l15) * 72 + ks * 32 + quad * 8];
            bf[tt][ks] = *(const short8*)&Bl[(wc + tt * 16 + l15) * 72 + ks * 32 + quad * 8];
        }
    __syncthreads();

    f32x4 acc[4][4];
#pragma unroll
    for (int rt = 0; rt < 4; rt++)
#pragma unroll
        for (int ct = 0; ct < 4; ct++) {
            f32x4 c = {0.f, 0.f, 0.f, 0.f};
            c = __builtin_amdgcn_mfma_f32_16x16x32_bf16(af[rt][0], bf[ct][0], c, 0, 0, 0);
            c = __builtin_amdgcn_mfma_f32_16x16x32_bf16(af[rt][1], bf[ct][1], c, 0, 0, 0);
            acc[rt][ct] = c;
        }

    float rs[4][4];
#pragma unroll
    for (int rt = 0; rt < 4; rt++)
#pragma unroll
        for (int g = 0; g < 4; g++) rs[rt][g] = 0.f;
    float cs[4] = {0.f, 0.f, 0.f, 0.f};

    bool interior = (i0 + 128 <= PN) && (j0 + 128 <= PN) && (i0 != j0);
    if (interior) {
#pragma unroll
        for (int rt = 0; rt < 4; rt++)
#pragma unroll
            for (int ct = 0; ct < 4; ct++) {
                float csum = 0.f;
#pragma unroll
                for (int g = 0; g < 4; g++) {
                    float e = __expf(acc[rt][ct][g] * INV_T);
                    rs[rt][g] += e;
                    csum += e;
                }
                cs[ct] += csum;
            }
    } else {
#pragma unroll
        for (int rt = 0; rt < 4; rt++) {
            int ibase = i0 + wr + rt * 16 + quad * 4;
#pragma unroll
            for (int ct = 0; ct < 4; ct++) {
                int j = j0 + wc + ct * 16 + l15;
                bool jv = (j < PN);
                float csum = 0.f;
#pragma unroll
                for (int g = 0; g < 4; g++) {
                    int i = ibase + g;
                    float e = 0.f;
                    if (jv && i < PN) {
                        e = __expf(acc[rt][ct][g] * INV_T);
                        if (i == j) A.pos[i] = e;
                    }
                    rs[rt][g] += e;
                    csum += e;
                }
                cs[ct] += csum;
            }
        }
    }
#pragma unroll
    for (int off = 16; off <= 32; off <<= 1)
#pragma unroll
        for (int ct = 0; ct < 4; ct++) cs[ct] += __shfl_xor(cs[ct], off, 64);
    if (quad == 0) {
#pragma unroll
        for (int ct = 0; ct < 4; ct++) {
            int j = j0 + wc + ct * 16 + l15;
            if (j < PN) atomicAdd(&A.colsum[j], cs[ct]);
        }
    }
    int slot = (wv >> 1) * 16 + l15;
#pragma unroll
    for (int rt = 0; rt < 4; rt++)
#pragma unroll
        for (int g = 0; g < 4; g++) {
            int rl = wr + rt * 16 + quad * 4 + g;
            red[slot * 131 + rl] = rs[rt][g];
        }
    __syncthreads();
    if (tid < 128) {
        float sum = 0.f;
#pragma unroll
        for (int s2 = 0; s2 < 32; s2++) sum += red[s2 * 131 + tid];
        int i = i0 + tid;
        if (i < PN) atomicAdd(&A.rowsum[i], sum);
    }
}

__device__ void dev_fuse(int u, const MArgs& A, char* smem) {
    float* msg = (float*)smem;   // 4 * 448 f32
    int tid = threadIdx.x, lane = tid & 63, r = tid >> 6;
    int row = u * 4 + r;
    float a0 = 0.f, a1 = 0.f, a2 = 0.f;
    {
        int s = A.up_rp[row], e = A.up_rp[row + 1];
        for (int p = s; p < e; ++p) {
            int i = A.up_ent[p];
            float v = A.up_vals[i];
            size_t o = (size_t)A.up_cols[i] * 64 + lane;
            a0 = fmaf(v, A.P0[o], a0);
            a1 = fmaf(v, A.P1[o], a1);
            a2 = fmaf(v, A.P4[o], a2);
        }
    }
    msg[r * 448 + 0 * 64 + lane] = a0;
    msg[r * 448 + 1 * 64 + lane] = a1;
    msg[r * 448 + 2 * 64 + lane] = a2;
    msg[r * 448 + 3 * 64 + lane] = a0 * a1;
    msg[r * 448 + 4 * 64 + lane] = a0 * a2;
    msg[r * 448 + 5 * 64 + lane] = a1 * a2;
    msg[r * 448 + 6 * 64 + lane] = a0 * a1 * a2;
    __syncthreads();
    float acc = A.fb[lane];
#pragma unroll 8
    for (int k = 0; k < 448; k++) acc = fmaf(msg[r * 448 + k], A.fw[k * 64 + lane], acc);
    size_t o = (size_t)row * 64 + lane;
    float uu = A.uemb[o];
    A.U0[o] = acc + uu + acc * uu;
}

__global__ __launch_bounds__(256) void infonce_fuse_kernel(MArgs A) {
    __shared__ __align__(16) char smem[36864];
    int u = blockIdx.x;
    if (u < 6241) dev_infonce(u, A, smem);
    else          dev_fuse(u - 6241, A, smem);
}

// ================= D10: pu spmm + col_g add + fusion_out =================
__global__ void puout_kernel(MArgs A) {
    int lane = threadIdx.x & 63;
    int row = blockIdx.x * 4 + (threadIdx.x >> 6);
    size_t o = (size_t)row * 64 + lane;
    float acc = A.P4[o];          // col_g
    int s = A.pu_rp[row], e = A.pu_rp[row + 1];
    int p = s;
    for (; p + 4 <= e; p += 4) {
        int i0 = A.pu_ent[p], i1 = A.pu_ent[p + 1], i2 = A.pu_ent[p + 2], i3 = A.pu_ent[p + 3];
        float v0 = A.pu_vals[i0], v1 = A.pu_vals[i1], v2 = A.pu_vals[i2], v3 = A.pu_vals[i3];
        float w0 = A.U0[(size_t)A.pu_cols[i0] * 64 + lane];
        float w1 = A.U0[(size_t)A.pu_cols[i1] * 64 + lane];
        float w2 = A.U0[(size_t)A.pu_cols[i2] * 64 + lane];
        float w3 = A.U0[(size_t)A.pu_cols[i3] * 64 + lane];
        acc = fmaf(v0, w0, acc);
        acc = fmaf(v1, w1, acc);
        acc = fmaf(v2, w2, acc);
        acc = fmaf(v3, w3, acc);
    }
    for (; p < e; ++p) {
        int i = A.pu_ent[p];
        acc = fmaf(A.pu_vals[i], A.U0[(size_t)A.pu_cols[i] * 64 + lane], acc);
    }
    float ss = acc * acc;
#pragma unroll
    for (int off = 32; off > 0; off >>= 1) ss += __shfl_xor(ss, off, 64);
    float d = fmaxf(sqrtf(ss), 1e-12f);
    float f = acc / d + A.P0[o] + A.P1[o];
    A.P3[o] = f;
    A.out_fp[o] = f;
}

// ================= D12: batch_users + loss =================
__global__ void batch_loss_kernel(MArgs A) {
    __shared__ float red[256];
    int tid = threadIdx.x;
    if ((int)blockIdx.x < 1024) {
        int lane = tid & 63;
        int b = blockIdx.x * 4 + (tid >> 6);
        int r = A.user_idx[b];
        float v = A.U0[(size_t)r * 64 + lane];
        float s = v * v;
#pragma unroll
        for (int off = 32; off > 0; off >>= 1) s += __shfl_xor(s, off, 64);
        float d = fmaxf(sqrtf(s), 1e-12f);
        A.out_bu[(size_t)b * 64 + lane] = v / d;
        return;
    }
    float acc = 0.0f;
    for (int i = tid; i < PN; i += 256) {
        float p = A.pos[i];
        acc += -logf(p / (A.rowsum[i] + 1e-8f) + 1e-8f);
        acc += -logf(p / (A.colsum[i] + 1e-8f) + 1e-8f);
    }
    red[tid] = acc;
    __syncthreads();
    for (int s = 128; s > 0; s >>= 1) {
        if (tid < s) red[tid] += red[tid + s];
        __syncthreads();
    }
    if (tid == 0) A.out_loss[0] = 0.5f * red[0] / (float)PN;
}

extern "C" void kernel_launch(void* const* d_in, const int* in_sizes, int n_in,
                              void* d_out, int out_size, void* d_ws, size_t ws_size,
                              hipStream_t stream) {
    (void)in_sizes; (void)n_in; (void)out_size; (void)ws_size;
    const int PD = PN * 64, UD = UN * 64;

    MArgs A;
    A.poi  = (const float*)d_in[0];
    A.uemb = (const float*)d_in[1];
    A.wgg  = (const float*)d_in[2];
    A.bgg  = (const float*)d_in[3];
    A.wgs  = (const float*)d_in[4];
    A.bgs  = (const float*)d_in[5];
    A.wgc  = (const float*)d_in[6];
    A.bgc  = (const float*)d_in[7];
    A.fw   = (const float*)d_in[8];
    A.fb   = (const float*)d_in[9];
    A.geo_vals = (const float*)d_in[10];
    A.src_vals = (const float*)d_in[11];
    A.tar_vals = (const float*)d_in[12];
    A.up_vals  = (const float*)d_in[13];
    A.pu_vals  = (const float*)d_in[14];
    A.geo_rows = (const int*)d_in[15];
    A.geo_cols = (const int*)d_in[16];
    A.src_rows = (const int*)d_in[17];
    A.src_cols = (const int*)d_in[18];
    A.tar_rows = (const int*)d_in[19];
    A.tar_cols = (const int*)d_in[20];
    A.up_rows  = (const int*)d_in[21];
    A.up_cols  = (const int*)d_in[22];
    A.pu_rows  = (const int*)d_in[23];
    A.pu_cols  = (const int*)d_in[24];
    A.user_idx = (const int*)d_in[25];

    float* F = (float*)d_ws;
    A.rowsum = F;
    A.colsum = A.rowsum + PN;
    A.pos    = A.colsum + PN;
    A.ngb    = (u16*)(F + 3 * PN);
    A.nsb    = A.ngb + PD;
    A.U0     = F + 3 * PN + PD;
    A.P0     = A.U0 + UD;
    A.P1     = A.P0 + PD;
    A.P2     = A.P1 + PD;
    A.P3     = A.P2 + PD;
    A.P4     = A.P3 + PD;
    A.M      = (int*)(A.P4 + PD);
    A.geo_rp = A.M;                  A.geo_cur = A.geo_rp + PN + 1;
    A.tar_rp = A.geo_cur + PN;       A.tar_cur = A.tar_rp + PN + 1;
    A.src_rp = A.tar_cur + PN;       A.src_cur = A.src_rp + PN + 1;
    A.up_rp  = A.src_cur + PN;       A.up_cur  = A.up_rp + UN + 1;
    A.pu_rp  = A.up_cur + UN;        A.pu_cur  = A.pu_rp + PN + 1;
    A.geo_ent = A.M + META_INTS;
    A.tar_ent = A.geo_ent + NGE;
    A.src_ent = A.tar_ent + NDE;
    A.up_ent  = A.src_ent + NDE;
    A.pu_ent  = A.up_ent + NUE;

    A.out_bu = (float*)d_out;
    A.out_fp = A.out_bu + (size_t)BN * 64;
    A.out_loss = A.out_fp + (size_t)PN * 64;

    const int NTOTB = (E4 + 255) / 256;            // 6875

    // D1: zero stats + counters
    zero_kernel<<<(ZN + 255) / 256, 256, 0, stream>>>(A);
    // D2: hist + geo/seq gates
    hist_gates_kernel<<<NTOTB + 5000, 256, 0, stream>>>(A);
    // D3: scans
    scan_kernel<<<5, 256, 0, stream>>>(A);
    // D4: scatter 4B edge indices
    scatter_kernel<<<NTOTB, 256, 0, stream>>>(A);
    // D5: geo1 || tar1
    spmm_step_kernel<<<5000, 256, 0, stream>>>(A, 0);
    // D6: geo2-final (ng) || s1
    spmm_step_kernel<<<5000, 256, 0, stream>>>(A, 1);
    // D7: tar2 || gate_col
    spmm_step_kernel<<<5000, 256, 0, stream>>>(A, 2);
    // D8: s2-final (ns)
    spmm_step_kernel<<<2500, 256, 0, stream>>>(A, 3);
    // D9: InfoNCE (MFMA) || spmm3+fuse_users
    infonce_fuse_kernel<<<6241 + 2000, 256, 0, stream>>>(A);
    // D10: pu spmm + fusion_out
    puout_kernel<<<2500, 256, 0, stream>>>(A);
    // D11: users_struct = up * fusion
    spmm_step_kernel<<<2000, 256, 0, stream>>>(A, 4);
    // D12: batch_users + loss
    batch_loss_kernel<<<1025, 256, 0, stream>>>(A);
}

// Round 10
// 670.438 us; speedup vs baseline: 2.2135x; 1.1340x over previous
//
#include <hip/hip_runtime.h>

#define PN 10000
#define UN 8000
#define BN 4096
#define NGE 320000
#define NDE 320000
#define NUE 400000
#define NPUE 400000
#define INV_T 5.0f
// cumulative edge offsets: geo, tar, src, up, pu
#define E0 320000
#define E1 640000
#define E2 960000
#define E3 1360000
#define E4 1760000
#define META_INTS 96006
#define ZN (3 * PN + META_INTS)

typedef __attribute__((ext_vector_type(8))) short short8;
typedef __attribute__((ext_vector_type(4))) float f32x4;
typedef unsigned short u16;
typedef unsigned int u32;

__device__ __forceinline__ u16 f2bf(float x) {
    u32 u = __float_as_uint(x);
    return (u16)((u + 0x7FFFu + ((u >> 16) & 1u)) >> 16);
}

struct MArgs {
    const float *poi, *uemb, *wgg, *bgg, *wgs, *bgs, *wgc, *bgc, *fw, *fb;
    const float *geo_vals, *src_vals, *tar_vals, *up_vals, *pu_vals;
    const int *geo_rows, *geo_cols, *src_rows, *src_cols, *tar_rows, *tar_cols;
    const int *up_rows, *up_cols, *pu_rows, *pu_cols, *user_idx;
    float *rowsum, *colsum, *pos;
    u16 *ngb, *nsb;
    float *U0, *P0, *P1, *P2, *P3, *P4;
    int *M;
    int *geo_rp, *geo_cur, *tar_rp, *tar_cur, *src_rp, *src_cur;
    int *up_rp, *up_cur, *pu_rp, *pu_cur;
    int *geo_ent, *tar_ent, *src_ent, *up_ent, *pu_ent;   // 4B local edge idx
    float *out_bu, *out_fp, *out_loss;
};

// ---------------- CSR SpMM core (4B edge-index entries; wave per row) ----------------
// ALIAS RULES: y may alias add/avg_a/avg_b (same-thread elementwise); y must NEVER alias x.
__device__ __forceinline__ void dev_spmm4(int row, int lane,
        const int* __restrict__ rp, const int* __restrict__ ent,
        const int* __restrict__ cols, const float* __restrict__ vals,
        const float* __restrict__ x, const float* __restrict__ add,
        const float* __restrict__ avg_a, const float* __restrict__ avg_b,
        float* __restrict__ y, u16* __restrict__ yb, int nrows, int mode) {
    if (row >= nrows) return;
    size_t o = (size_t)row * 64 + lane;
    int s = rp[row], e = rp[row + 1];
    float acc = add ? add[o] : 0.0f;
    int p = s;
    for (; p + 4 <= e; p += 4) {
        int i0 = ent[p], i1 = ent[p + 1], i2 = ent[p + 2], i3 = ent[p + 3];
        int c0 = cols[i0], c1 = cols[i1], c2 = cols[i2], c3 = cols[i3];
        float v0 = vals[i0], v1 = vals[i1], v2 = vals[i2], v3 = vals[i3];
        float w0 = x[(size_t)c0 * 64 + lane];
        float w1 = x[(size_t)c1 * 64 + lane];
        float w2 = x[(size_t)c2 * 64 + lane];
        float w3 = x[(size_t)c3 * 64 + lane];
        acc = fmaf(v0, w0, acc);
        acc = fmaf(v1, w1, acc);
        acc = fmaf(v2, w2, acc);
        acc = fmaf(v3, w3, acc);
    }
    for (; p < e; ++p) {
        int i = ent[p];
        acc = fmaf(vals[i], x[(size_t)cols[i] * 64 + lane], acc);
    }
    if (mode == 0) { y[o] = acc; return; }
    float v = (avg_a[o] + avg_b[o] + acc) * (1.0f / 3.0f);
    float ss = v * v;
#pragma unroll
    for (int off = 32; off > 0; off >>= 1) ss += __shfl_xor(ss, off, 64);
    float d = fmaxf(sqrtf(ss), 1e-12f);
    float r = v / d;
    y[o] = r;
    yb[o] = f2bf(r);
}

// ---------------- single gate: out = pe * sigmoid(pe @ W + b) ----------------
__device__ void dev_gate(int u, const float* __restrict__ poi, const float* __restrict__ wg,
                         const float* __restrict__ bg, float* __restrict__ og, char* smem) {
    float* W  = (float*)smem;                    // 4096 f32
    float* Bv = (float*)(smem + 16384);          // 64 f32
    float* pe = (float*)(smem + 16384 + 256);    // 256 f32
    int tid = threadIdx.x;
    for (int t = tid; t < 4096; t += 256) W[t] = wg[t];
    if (tid < 64) Bv[tid] = bg[tid];
    int r = tid >> 6, j = tid & 63;
    int r0 = u * 4;
    pe[r * 64 + j] = poi[(r0 + r) * 64 + j];
    __syncthreads();
    float acc = Bv[j];
#pragma unroll
    for (int k = 0; k < 64; k++) acc = fmaf(pe[r * 64 + k], W[k * 64 + j], acc);
    float pj = pe[r * 64 + j];
    og[(r0 + r) * 64 + j] = pj * (1.0f / (1.0f + __expf(-acc)));
}

// ================= D1: zero stats + CSR counters =================
__global__ void zero_kernel(MArgs A) {
    int i = blockIdx.x * 256 + threadIdx.x;
    if (i < 3 * PN) A.rowsum[i] = 0.0f;
    else if (i < ZN) A.M[i - 3 * PN] = 0;
}

// ================= D2: hist (6875) + geo/seq gates (2x2500) =================
__global__ void hist_gates_kernel(MArgs A) {
    __shared__ __align__(16) char smem[17664];
    int u = blockIdx.x;
    if (u < 6875) {
        int e = u * 256 + threadIdx.x;
        if (e < E0)      atomicAdd(&A.geo_cur[A.geo_rows[e]], 1);
        else if (e < E1) atomicAdd(&A.tar_cur[A.tar_rows[e - E0]], 1);
        else if (e < E2) atomicAdd(&A.src_cur[A.src_rows[e - E1]], 1);
        else if (e < E3) atomicAdd(&A.up_cur[A.up_rows[e - E2]], 1);
        else if (e < E4) atomicAdd(&A.pu_cur[A.pu_rows[e - E3]], 1);
    } else if (u < 6875 + 2500) {
        dev_gate(u - 6875, A.poi, A.wgg, A.bgg, A.P0, smem);          // geo_g -> P0
    } else {
        dev_gate(u - 9375, A.poi, A.wgs, A.bgs, A.P1, smem);          // seq_g -> P1
    }
}

// ================= D3: 5 scans =================
__global__ void scan_kernel(MArgs A) {
    __shared__ int part[256];
    int* cnt; int* rp; int n; int nnz;
    switch (blockIdx.x) {
        case 0: cnt = A.geo_cur; rp = A.geo_rp; n = PN; nnz = NGE; break;
        case 1: cnt = A.tar_cur; rp = A.tar_rp; n = PN; nnz = NDE; break;
        case 2: cnt = A.src_cur; rp = A.src_rp; n = PN; nnz = NDE; break;
        case 3: cnt = A.up_cur;  rp = A.up_rp;  n = UN; nnz = NUE; break;
        default: cnt = A.pu_cur; rp = A.pu_rp;  n = PN; nnz = NPUE; break;
    }
    int tid = threadIdx.x;
    int chunk = (n + 255) >> 8;
    int base = tid * chunk;
    int s = 0;
    for (int k = 0; k < chunk; k++) {
        int i = base + k;
        if (i < n) s += cnt[i];
    }
    part[tid] = s;
    __syncthreads();
    for (int off = 1; off < 256; off <<= 1) {
        int v = (tid >= off) ? part[tid - off] : 0;
        __syncthreads();
        part[tid] += v;
        __syncthreads();
    }
    int pre = (tid > 0) ? part[tid - 1] : 0;
    for (int k = 0; k < chunk; k++) {
        int i = base + k;
        if (i < n) {
            int c = cnt[i];
            rp[i] = pre;
            cnt[i] = pre;   // becomes cursor
            pre += c;
        }
    }
    if (tid == 0) rp[n] = nnz;
}

// ================= D4: scatter 4B local edge idx =================
__global__ void scatter_kernel(MArgs A) {
    int e = blockIdx.x * 256 + threadIdx.x;
    const int* rr; int* cu; int* en; int idx;
    if (e < E0)      { rr = A.geo_rows; cu = A.geo_cur; en = A.geo_ent; idx = e; }
    else if (e < E1) { rr = A.tar_rows; cu = A.tar_cur; en = A.tar_ent; idx = e - E0; }
    else if (e < E2) { rr = A.src_rows; cu = A.src_cur; en = A.src_ent; idx = e - E1; }
    else if (e < E3) { rr = A.up_rows;  cu = A.up_cur;  en = A.up_ent;  idx = e - E2; }
    else if (e < E4) { rr = A.pu_rows;  cu = A.pu_cur;  en = A.pu_ent;  idx = e - E3; }
    else return;
    int p = atomicAdd(&cu[rr[idx]], 1);
    en[p] = idx;
}

// ================= D5-D8, D12: SpMM phases =================
// step 0: geo1 (x1_g=A*g+g: P0->P3) || tar1 (m1=T*sg: P1->P4)          grid 5000
// step 1: geo2fin (x2=A*x1+x1; ng->P0,ngb) || s1 (x1_s=S*m1+sg: ->P2)  grid 5000
// step 2: tar2 (m2=T*x1_s: P2->P3) || gate_col (->P4)                  grid 5000
// step 3: s2fin (x2=S*m2+x1_s; ns->P1,nsb)                             grid 2500
// step 4: users_struct = up * fusion(P3) -> U0                         grid 2000
__global__ __launch_bounds__(256) void spmm_step_kernel(MArgs A, int step) {
    __shared__ __align__(16) char smem[17664];
    int tid = threadIdx.x;
    int lane = tid & 63, w = tid >> 6;
    int u = blockIdx.x;
    if (step == 0) {
        if (u < 2500) dev_spmm4(u * 4 + w, lane, A.geo_rp, A.geo_ent, A.geo_cols, A.geo_vals,
                                A.P0, A.P0, nullptr, nullptr, A.P3, nullptr, PN, 0);
        else dev_spmm4((u - 2500) * 4 + w, lane, A.tar_rp, A.tar_ent, A.tar_cols, A.tar_vals,
                       A.P1, nullptr, nullptr, nullptr, A.P4, nullptr, PN, 0);
    } else if (step == 1) {
        if (u < 2500) dev_spmm4(u * 4 + w, lane, A.geo_rp, A.geo_ent, A.geo_cols, A.geo_vals,
                                A.P3, A.P3, A.P0, A.P3, A.P0, A.ngb, PN, 1);
        else dev_spmm4((u - 2500) * 4 + w, lane, A.src_rp, A.src_ent, A.src_cols, A.src_vals,
                       A.P4, A.P1, nullptr, nullptr, A.P2, nullptr, PN, 0);
    } else if (step == 2) {
        if (u < 2500) dev_spmm4(u * 4 + w, lane, A.tar_rp, A.tar_ent, A.tar_cols, A.tar_vals,
                                A.P2, nullptr, nullptr, nullptr, A.P3, nullptr, PN, 0);
        else dev_gate(u - 2500, A.poi, A.wgc, A.bgc, A.P4, smem);
    } else if (step == 3) {
        dev_spmm4(u * 4 + w, lane, A.src_rp, A.src_ent, A.src_cols, A.src_vals,
                  A.P3, A.P2, A.P1, A.P2, A.P1, A.nsb, PN, 1);
    } else {
        dev_spmm4(u * 4 + w, lane, A.up_rp, A.up_ent, A.up_cols, A.up_vals,
                  A.P3, nullptr, nullptr, nullptr, A.U0, nullptr, UN, 0);
    }
}

// ================= D9: MFMA InfoNCE (standalone — L2 keeps ngb/nsb resident) =================
__global__ __launch_bounds__(256) void infonce_kernel(MArgs A) {
    __shared__ __align__(16) char smraw[36864];
    u16* Al = (u16*)smraw;
    u16* Bl = (u16*)(smraw + 18432);
    float* red = (float*)smraw;      // reused after frags cached
    int tid = threadIdx.x;
    int bx = blockIdx.x % 79, by = blockIdx.x / 79;
    int i0 = bx * 128, j0 = by * 128;
    const uint4 zero4 = make_uint4(0, 0, 0, 0);
    for (int u = tid; u < 1024; u += 256) {
        int row = u >> 3, ch = u & 7;
        int ga = i0 + row, gb = j0 + row;
        uint4 va = (ga < PN) ? ((const uint4*)A.ngb)[(size_t)ga * 8 + ch] : zero4;
        uint4 vb = (gb < PN) ? ((const uint4*)A.nsb)[(size_t)gb * 8 + ch] : zero4;
        ((uint4*)Al)[row * 9 + ch] = va;
        ((uint4*)Bl)[row * 9 + ch] = vb;
    }
    __syncthreads();
    int wv = tid >> 6, lane = tid & 63;
    int wr = (wv & 1) * 64;
    int wc = (wv >> 1) * 64;
    int quad = lane >> 4, l15 = lane & 15;

    short8 af[4][2], bf[4][2];
#pragma unroll
    for (int tt = 0; tt < 4; tt++)
#pragma unroll
        for (int ks = 0; ks < 2; ks++) {
            af[tt][ks] = *(const short8*)&Al[(wr + tt * 16 + l15) * 72 + ks * 32 + quad * 8];
            bf[tt][ks] = *(const short8*)&Bl[(wc + tt * 16 + l15) * 72 + ks * 32 + quad * 8];
        }
    __syncthreads();

    f32x4 acc[4][4];
#pragma unroll
    for (int rt = 0; rt < 4; rt++)
#pragma unroll
        for (int ct = 0; ct < 4; ct++) {
            f32x4 c = {0.f, 0.f, 0.f, 0.f};
            c = __builtin_amdgcn_mfma_f32_16x16x32_bf16(af[rt][0], bf[ct][0], c, 0, 0, 0);
            c = __builtin_amdgcn_mfma_f32_16x16x32_bf16(af[rt][1], bf[ct][1], c, 0, 0, 0);
            acc[rt][ct] = c;
        }

    float rs[4][4];
#pragma unroll
    for (int rt = 0; rt < 4; rt++)
#pragma unroll
        for (int g = 0; g < 4; g++) rs[rt][g] = 0.f;
    float cs[4] = {0.f, 0.f, 0.f, 0.f};

    bool interior = (i0 + 128 <= PN) && (j0 + 128 <= PN) && (i0 != j0);
    if (interior) {
#pragma unroll
        for (int rt = 0; rt < 4; rt++)
#pragma unroll
            for (int ct = 0; ct < 4; ct++) {
                float csum = 0.f;
#pragma unroll
                for (int g = 0; g < 4; g++) {
                    float e = __expf(acc[rt][ct][g] * INV_T);
                    rs[rt][g] += e;
                    csum += e;
                }
                cs[ct] += csum;
            }
    } else {
#pragma unroll
        for (int rt = 0; rt < 4; rt++) {
            int ibase = i0 + wr + rt * 16 + quad * 4;
#pragma unroll
            for (int ct = 0; ct < 4; ct++) {
                int j = j0 + wc + ct * 16 + l15;
                bool jv = (j < PN);
                float csum = 0.f;
#pragma unroll
                for (int g = 0; g < 4; g++) {
                    int i = ibase + g;
                    float e = 0.f;
                    if (jv && i < PN) {
                        e = __expf(acc[rt][ct][g] * INV_T);
                        if (i == j) A.pos[i] = e;
                    }
                    rs[rt][g] += e;
                    csum += e;
                }
                cs[ct] += csum;
            }
        }
    }
#pragma unroll
    for (int off = 16; off <= 32; off <<= 1)
#pragma unroll
        for (int ct = 0; ct < 4; ct++) cs[ct] += __shfl_xor(cs[ct], off, 64);
    if (quad == 0) {
#pragma unroll
        for (int ct = 0; ct < 4; ct++) {
            int j = j0 + wc + ct * 16 + l15;
            if (j < PN) atomicAdd(&A.colsum[j], cs[ct]);
        }
    }
    int slot = (wv >> 1) * 16 + l15;
#pragma unroll
    for (int rt = 0; rt < 4; rt++)
#pragma unroll
        for (int g = 0; g < 4; g++) {
            int rl = wr + rt * 16 + quad * 4 + g;
            red[slot * 131 + rl] = rs[rt][g];
        }
    __syncthreads();
    if (tid < 128) {
        float sum = 0.f;
#pragma unroll
        for (int s2 = 0; s2 < 32; s2++) sum += red[s2 * 131 + tid];
        int i = i0 + tid;
        if (i < PN) atomicAdd(&A.rowsum[i], sum);
    }
}

// ================= D10: spmm3(up) + fuse_users (separate dispatch) =================
__global__ void fuse_kernel(MArgs A) {
    __shared__ float msg[4][448];
    int tid = threadIdx.x, lane = tid & 63, r = tid >> 6;
    int row = blockIdx.x * 4 + r;
    float a0 = 0.f, a1 = 0.f, a2 = 0.f;
    {
        int s = A.up_rp[row], e = A.up_rp[row + 1];
        for (int p = s; p < e; ++p) {
            int i = A.up_ent[p];
            float v = A.up_vals[i];
            size_t o = (size_t)A.up_cols[i] * 64 + lane;
            a0 = fmaf(v, A.P0[o], a0);
            a1 = fmaf(v, A.P1[o], a1);
            a2 = fmaf(v, A.P4[o], a2);
        }
    }
    msg[r][0 * 64 + lane] = a0;
    msg[r][1 * 64 + lane] = a1;
    msg[r][2 * 64 + lane] = a2;
    msg[r][3 * 64 + lane] = a0 * a1;
    msg[r][4 * 64 + lane] = a0 * a2;
    msg[r][5 * 64 + lane] = a1 * a2;
    msg[r][6 * 64 + lane] = a0 * a1 * a2;
    __syncthreads();
    float acc = A.fb[lane];
#pragma unroll 8
    for (int k = 0; k < 448; k++) acc = fmaf(msg[r][k], A.fw[k * 64 + lane], acc);
    size_t o = (size_t)row * 64 + lane;
    float uu = A.uemb[o];
    A.U0[o] = acc + uu + acc * uu;
}

// ================= D11: pu spmm + col_g add + fusion_out =================
__global__ void puout_kernel(MArgs A) {
    int lane = threadIdx.x & 63;
    int row = blockIdx.x * 4 + (threadIdx.x >> 6);
    size_t o = (size_t)row * 64 + lane;
    float acc = A.P4[o];          // col_g
    int s = A.pu_rp[row], e = A.pu_rp[row + 1];
    int p = s;
    for (; p + 4 <= e; p += 4) {
        int i0 = A.pu_ent[p], i1 = A.pu_ent[p + 1], i2 = A.pu_ent[p + 2], i3 = A.pu_ent[p + 3];
        float v0 = A.pu_vals[i0], v1 = A.pu_vals[i1], v2 = A.pu_vals[i2], v3 = A.pu_vals[i3];
        float w0 = A.U0[(size_t)A.pu_cols[i0] * 64 + lane];
        float w1 = A.U0[(size_t)A.pu_cols[i1] * 64 + lane];
        float w2 = A.U0[(size_t)A.pu_cols[i2] * 64 + lane];
        float w3 = A.U0[(size_t)A.pu_cols[i3] * 64 + lane];
        acc = fmaf(v0, w0, acc);
        acc = fmaf(v1, w1, acc);
        acc = fmaf(v2, w2, acc);
        acc = fmaf(v3, w3, acc);
    }
    for (; p < e; ++p) {
        int i = A.pu_ent[p];
        acc = fmaf(A.pu_vals[i], A.U0[(size_t)A.pu_cols[i] * 64 + lane], acc);
    }
    float ss = acc * acc;
#pragma unroll
    for (int off = 32; off > 0; off >>= 1) ss += __shfl_xor(ss, off, 64);
    float d = fmaxf(sqrtf(ss), 1e-12f);
    float f = acc / d + A.P0[o] + A.P1[o];
    A.P3[o] = f;
    A.out_fp[o] = f;
}

// ================= D13: batch_users + loss =================
__global__ void batch_loss_kernel(MArgs A) {
    __shared__ float red[256];
    int tid = threadIdx.x;
    if ((int)blockIdx.x < 1024) {
        int lane = tid & 63;
        int b = blockIdx.x * 4 + (tid >> 6);
        int r = A.user_idx[b];
        float v = A.U0[(size_t)r * 64 + lane];
        float s = v * v;
#pragma unroll
        for (int off = 32; off > 0; off >>= 1) s += __shfl_xor(s, off, 64);
        float d = fmaxf(sqrtf(s), 1e-12f);
        A.out_bu[(size_t)b * 64 + lane] = v / d;
        return;
    }
    float acc = 0.0f;
    for (int i = tid; i < PN; i += 256) {
        float p = A.pos[i];
        acc += -logf(p / (A.rowsum[i] + 1e-8f) + 1e-8f);
        acc += -logf(p / (A.colsum[i] + 1e-8f) + 1e-8f);
    }
    red[tid] = acc;
    __syncthreads();
    for (int s = 128; s > 0; s >>= 1) {
        if (tid < s) red[tid] += red[tid + s];
        __syncthreads();
    }
    if (tid == 0) A.out_loss[0] = 0.5f * red[0] / (float)PN;
}

extern "C" void kernel_launch(void* const* d_in, const int* in_sizes, int n_in,
                              void* d_out, int out_size, void* d_ws, size_t ws_size,
                              hipStream_t stream) {
    (void)in_sizes; (void)n_in; (void)out_size; (void)ws_size;
    const int PD = PN * 64, UD = UN * 64;

    MArgs A;
    A.poi  = (const float*)d_in[0];
    A.uemb = (const float*)d_in[1];
    A.wgg  = (const float*)d_in[2];
    A.bgg  = (const float*)d_in[3];
    A.wgs  = (const float*)d_in[4];
    A.bgs  = (const float*)d_in[5];
    A.wgc  = (const float*)d_in[6];
    A.bgc  = (const float*)d_in[7];
    A.fw   = (const float*)d_in[8];
    A.fb   = (const float*)d_in[9];
    A.geo_vals = (const float*)d_in[10];
    A.src_vals = (const float*)d_in[11];
    A.tar_vals = (const float*)d_in[12];
    A.up_vals  = (const float*)d_in[13];
    A.pu_vals  = (const float*)d_in[14];
    A.geo_rows = (const int*)d_in[15];
    A.geo_cols = (const int*)d_in[16];
    A.src_rows = (const int*)d_in[17];
    A.src_cols = (const int*)d_in[18];
    A.tar_rows = (const int*)d_in[19];
    A.tar_cols = (const int*)d_in[20];
    A.up_rows  = (const int*)d_in[21];
    A.up_cols  = (const int*)d_in[22];
    A.pu_rows  = (const int*)d_in[23];
    A.pu_cols  = (const int*)d_in[24];
    A.user_idx = (const int*)d_in[25];

    float* F = (float*)d_ws;
    A.rowsum = F;
    A.colsum = A.rowsum + PN;
    A.pos    = A.colsum + PN;
    A.ngb    = (u16*)(F + 3 * PN);
    A.nsb    = A.ngb + PD;
    A.U0     = F + 3 * PN + PD;
    A.P0     = A.U0 + UD;
    A.P1     = A.P0 + PD;
    A.P2     = A.P1 + PD;
    A.P3     = A.P2 + PD;
    A.P4     = A.P3 + PD;
    A.M      = (int*)(A.P4 + PD);
    A.geo_rp = A.M;                  A.geo_cur = A.geo_rp + PN + 1;
    A.tar_rp = A.geo_cur + PN;       A.tar_cur = A.tar_rp + PN + 1;
    A.src_rp = A.tar_cur + PN;       A.src_cur = A.src_rp + PN + 1;
    A.up_rp  = A.src_cur + PN;       A.up_cur  = A.up_rp + UN + 1;
    A.pu_rp  = A.up_cur + UN;        A.pu_cur  = A.pu_rp + PN + 1;
    A.geo_ent = A.M + META_INTS;
    A.tar_ent = A.geo_ent + NGE;
    A.src_ent = A.tar_ent + NDE;
    A.up_ent  = A.src_ent + NDE;
    A.pu_ent  = A.up_ent + NUE;

    A.out_bu = (float*)d_out;
    A.out_fp = A.out_bu + (size_t)BN * 64;
    A.out_loss = A.out_fp + (size_t)PN * 64;

    const int NTOTB = (E4 + 255) / 256;            // 6875

    // D1: zero stats + counters
    zero_kernel<<<(ZN + 255) / 256, 256, 0, stream>>>(A);
    // D2: hist + geo/seq gates
    hist_gates_kernel<<<NTOTB + 5000, 256, 0, stream>>>(A);
    // D3: scans
    scan_kernel<<<5, 256, 0, stream>>>(A);
    // D4: scatter 4B edge indices
    scatter_kernel<<<NTOTB, 256, 0, stream>>>(A);
    // D5: geo1 || tar1
    spmm_step_kernel<<<5000, 256, 0, stream>>>(A, 0);
    // D6: geo2-final (ng) || s1
    spmm_step_kernel<<<5000, 256, 0, stream>>>(A, 1);
    // D7: tar2 || gate_col
    spmm_step_kernel<<<5000, 256, 0, stream>>>(A, 2);
    // D8: s2-final (ns)
    spmm_step_kernel<<<2500, 256, 0, stream>>>(A, 3);
    // D9: InfoNCE (MFMA) — STANDALONE so ngb/nsb stay L2-resident
    infonce_kernel<<<6241, 256, 0, stream>>>(A);
    // D10: spmm3(up) + fuse_users
    fuse_kernel<<<2000, 256, 0, stream>>>(A);
    // D11: pu spmm + fusion_out
    puout_kernel<<<2500, 256, 0, stream>>>(A);
    // D12: users_struct = up * fusion
    spmm_step_kernel<<<2000, 256, 0, stream>>>(A, 4);
    // D13: batch_users + loss
    batch_loss_kernel<<<1025, 256, 0, stream>>>(A);
}